// Round 6
// baseline (71.842 us; speedup 1.0000x reference)
//
#include <hip/hip_runtime.h>

// 5-qubit state, ONE patch per thread, wire-0 pair packed in float2 lanes:
// m = bits[3:0] = wires 1..4 (b,c,d,e); .x = wire0(a)=0 amp, .y = a=1 amp.
// Every RX/CU gate ignores wire0 -> elementwise-identical across the packed
// pair. CPhase and the final H/<Z0> are the only wire0-touching ops.
// Plain float2 arithmetic (no inline asm): compiler free to emit v_pk or
// scalar v_fma; FLOP floor identical either way (pk_f32 is 4cyc = 2x scalar).
// PITFALL (r2-3): neg_lo/neg_hi on v_pk_*_f32 inline asm is broken on gfx950.
// Grid: 262144 threads = 4096 waves = 4 waves/SIMD (2x the patch-pair version).

typedef float f2 __attribute__((ext_vector_type(2)));

// sin/cos of ang/2 via native v_sin/v_cos (input in revolutions; |rev|<0.5 here).
__device__ __forceinline__ void sc_half(float ang, float& s, float& c) {
    const float r = ang * 0.07957747154594767f;   // (ang/2) / (2*pi)
    s = __builtin_amdgcn_sinf(r);
    c = __builtin_amdgcn_cosf(r);
}
__device__ __forceinline__ void sc_full(float ang, float& s, float& c) {
    const float r = ang * 0.15915494309189535f;   // ang / (2*pi)
    s = __builtin_amdgcn_sinf(r);
    c = __builtin_amdgcn_cosf(r);
}

template<int BIT>
__device__ __forceinline__ void apply_rx(f2 (&R)[16], f2 (&I)[16],
                                         float c, float s) {
    // gate [[c, -i*s], [-i*s, c]] on wire (4-BIT); elementwise over packed pair
#pragma unroll
    for (int m = 0; m < 8; ++m) {
        const int lo = m & ((1 << BIT) - 1);
        const int hi = (m >> BIT) << (BIT + 1);
        const int i0 = hi | lo;
        const int i1 = i0 | (1 << BIT);
        const f2 ar = R[i0], ai = I[i0];
        const f2 br = R[i1], bi = I[i1];
        R[i0] = c * ar + s * bi;
        I[i0] = c * ai - s * br;
        R[i1] = c * br + s * ai;
        I[i1] = c * bi - s * ar;
    }
}

// controlled-X_theta with u01 = sn - i*cs, u10 = -sn - i*cs (of theta/2).
template<int CBIT, int TBIT>
__device__ __forceinline__ void cu_gate(f2 (&R)[16], f2 (&I)[16],
                                        float sn, float cs) {
#pragma unroll
    for (int m = 0; m < 8; ++m) {
        const int lo = m & ((1 << TBIT) - 1);
        const int hi = (m >> TBIT) << (TBIT + 1);
        const int i0 = hi | lo;
        if (!(i0 & (1 << CBIT))) continue;   // compile-time eliminated
        const int i1 = i0 | (1 << TBIT);
        const f2 ar = R[i0], ai = I[i0];
        const f2 br = R[i1], bi = I[i1];
        R[i0] =  sn * br + cs * bi;
        I[i0] =  sn * bi - cs * br;
        R[i1] = -sn * ar + cs * ai;
        I[i1] = -sn * ai - cs * ar;
    }
}

// CPhase(phi) on wires 0,1: multiply amps with a=1 (.y) & b=1 (bit3) by e^{i phi}.
// Packed constants {1, e^{i phi}} -> .x half untouched, .y half rotated.
__device__ __forceinline__ void cphase(f2 (&R)[16], f2 (&I)[16],
                                       float sn, float cs) {
    const f2 C = {1.f, cs}, S = {0.f, sn};
#pragma unroll
    for (int m = 8; m < 16; ++m) {
        const f2 r = R[m], ii = I[m];
        R[m] = C * r  - S * ii;
        I[m] = C * ii + S * r;
    }
}

__global__ __launch_bounds__(256, 4)
void qsim_kernel(const float* __restrict__ x,
                 const float* __restrict__ thetas,
                 const float* __restrict__ phis,
                 float* __restrict__ out, int P) {
    const int p = blockIdx.x * blockDim.x + threadIdx.x;
    if (p >= P) return;

    const int b   = p >> 14;
    const int rem = p & 16383;
    const int i   = rem >> 7;
    const int j   = rem & 127;

    const float2* __restrict__ x2 = (const float2*)x;
    const long rowbase = (long)b * 768 + 2 * i;   // + c*256 + dy

    // ---- channel 0 loads ----
    float2 v0 = x2[(rowbase + 0) * 128 + j];
    float2 v1 = x2[(rowbase + 1) * 128 + j];

    // ---- fold H(wire0) + layer-0 RX into 16-amp product state ----
    // amp(m) = m(bcde) * (-i)^popcount(bcde); both packed halves identical.
    // (global 1/sqrt2 dropped; cancels the final factor-2 in <Z0>.)
    f2 R[16], I[16];
    {
        float s1, c1, s2, c2, s3, c3, s4, c4;
        sc_half(v0.x, s1, c1);
        sc_half(v0.y, s2, c2);
        sc_half(v1.x, s3, c3);
        sc_half(v1.y, s4, c4);
        const float pA[4] = {c1 * c2, c1 * s2, s1 * c2, s1 * s2}; // bits 3,2
        const float pB[4] = {c3 * c4, c3 * s4, s3 * c4, s3 * s4}; // bits 1,0
#pragma unroll
        for (int m = 0; m < 16; ++m) {
            const float v = pA[m >> 2] * pB[m & 3];
            const int pc = __builtin_popcount((unsigned)m) & 3;
            const float rr = (pc == 0) ? v : ((pc == 2) ? -v : 0.f);
            const float ii = (pc == 1) ? -v : ((pc == 3) ? v : 0.f);
            R[m] = (f2){rr, rr};
            I[m] = (f2){ii, ii};
        }
    }

    // issue channel-1 loads early (consumed in layer-1 RX)
    v0 = x2[(rowbase + 256) * 128 + j];
    v1 = x2[(rowbase + 257) * 128 + j];

    // ---- layer 0: CU gates (packed halves still identical -> computed free) ----
    {
        float sn, cs;
        sc_half(thetas[0], sn, cs); cu_gate<3, 2>(R, I, sn, cs);
        sc_half(thetas[1], sn, cs); cu_gate<2, 1>(R, I, sn, cs);
        sc_half(thetas[2], sn, cs); cu_gate<1, 0>(R, I, sn, cs);
        sc_half(thetas[3], sn, cs); cu_gate<0, 3>(R, I, sn, cs);
    }
    {
        float sn, cs;
        sc_full(phis[0], sn, cs);
        cphase(R, I, sn, cs);
    }

    // ---- layer 1 ----
    {
        float sn, cs;
        sc_half(v0.x, sn, cs); apply_rx<3>(R, I, cs, sn);
        sc_half(v0.y, sn, cs); apply_rx<2>(R, I, cs, sn);
        sc_half(v1.x, sn, cs); apply_rx<1>(R, I, cs, sn);
        sc_half(v1.y, sn, cs); apply_rx<0>(R, I, cs, sn);
    }
    // issue channel-2 loads early (consumed in layer-2 RX)
    v0 = x2[(rowbase + 512) * 128 + j];
    v1 = x2[(rowbase + 513) * 128 + j];

    {
        float sn, cs;
        sc_half(thetas[4], sn, cs); cu_gate<3, 2>(R, I, sn, cs);
        sc_half(thetas[5], sn, cs); cu_gate<2, 1>(R, I, sn, cs);
        sc_half(thetas[6], sn, cs); cu_gate<1, 0>(R, I, sn, cs);
        sc_half(thetas[7], sn, cs); cu_gate<0, 3>(R, I, sn, cs);
    }
    {
        float sn, cs;
        sc_full(phis[1], sn, cs);
        cphase(R, I, sn, cs);
    }

    // ---- layer 2 ----
    {
        float sn, cs;
        sc_half(v0.x, sn, cs); apply_rx<3>(R, I, cs, sn);
        sc_half(v0.y, sn, cs); apply_rx<2>(R, I, cs, sn);
        sc_half(v1.x, sn, cs); apply_rx<1>(R, I, cs, sn);
        sc_half(v1.y, sn, cs); apply_rx<0>(R, I, cs, sn);
    }
    {
        float sn, cs;
        sc_half(thetas[ 8], sn, cs); cu_gate<3, 2>(R, I, sn, cs);
        sc_half(thetas[ 9], sn, cs); cu_gate<2, 1>(R, I, sn, cs);
        sc_half(thetas[10], sn, cs); cu_gate<1, 0>(R, I, sn, cs);
        sc_half(thetas[11], sn, cs); cu_gate<0, 3>(R, I, sn, cs);
    }
    {
        float sn, cs;
        sc_full(phis[2], sn, cs);
        cphase(R, I, sn, cs);
    }

    // final H on wire0 + <Z0>: ev = sum_m Re(v_m * conj(w_m)),
    // v = .x half, w = .y half of each packed amp.
    float ev = 0.f;
#pragma unroll
    for (int m = 0; m < 16; ++m) {
        ev += R[m].x * R[m].y + I[m].x * I[m].y;
    }
    out[p] = ev;
}

extern "C" void kernel_launch(void* const* d_in, const int* in_sizes, int n_in,
                              void* d_out, int out_size, void* d_ws, size_t ws_size,
                              hipStream_t stream) {
    const float* x      = (const float*)d_in[0];
    const float* thetas = (const float*)d_in[1];
    const float* phis   = (const float*)d_in[2];
    float* out = (float*)d_out;
    const int P = out_size;               // 16 * 128 * 128 = 262144
    const int threads = 256;
    const int blocks = (P + threads - 1) / threads;
    qsim_kernel<<<blocks, threads, 0, stream>>>(x, thetas, phis, out, P);
}

// Round 7
// 71.682 us; speedup vs baseline: 1.0022x; 1.0022x over previous
//
#include <hip/hip_runtime.h>

// 5-qubit state, ONE patch per thread, wire-0 pair packed in float2 lanes:
// m = bits[3:0] = wires 1..4 (b,c,d,e); .x = wire0(a)=0 amp, .y = a=1 amp.
//
// KEY ALGEBRA (this round): controlled-X_theta = CNOT * C-diag. CNOT is a
// basis permutation (free: compile-time index relabel). A whole layer's
// CU x4 + CPhase block is therefore ONE static permutation
//   PI(m) = (m0^m1^m2, m2^m3, m1^m2^m3, m0^m1^m2^m3)
// plus ONE per-amp complex phase chi(m) (uniform; precomputed into d_ws).
// For the LAST layer, <Z0> = sum Re(v*conj(w)) is monomial-invariant, so the
// entire layer-2 CU block drops out; only e^{-i phi2} survives in the reduce
// (formula validated in round 1).
// PITFALL (r2-3): neg_lo/neg_hi on v_pk_*_f32 inline asm is broken on gfx950
// -> plain float2 arithmetic only, no asm.

typedef float f2 __attribute__((ext_vector_type(2)));

// sin/cos via native v_sin/v_cos (input in revolutions; |rev|<0.5 here).
__device__ __forceinline__ void sc_half(float ang, float& s, float& c) {
    const float r = ang * 0.07957747154594767f;   // (ang/2) / (2*pi)
    s = __builtin_amdgcn_sinf(r);
    c = __builtin_amdgcn_cosf(r);
}
__device__ __forceinline__ void sc_full(float ang, float& s, float& c) {
    const float r = ang * 0.15915494309189535f;   // ang / (2*pi)
    s = __builtin_amdgcn_sinf(r);
    c = __builtin_amdgcn_cosf(r);
}

// layer CU-block permutation (all-CNOTs pushed past the diagonals)
__host__ __device__ constexpr int PI_(int m) {
    const int m3 = (m >> 3) & 1, m2 = (m >> 2) & 1, m1 = (m >> 1) & 1, m0 = m & 1;
    return ((m0 ^ m1 ^ m2) << 3) | ((m2 ^ m3) << 2) |
           ((m1 ^ m2 ^ m3) << 1) | (m0 ^ m1 ^ m2 ^ m3);
}

template<int BIT>
__device__ __forceinline__ void apply_rx(f2 (&R)[16], f2 (&I)[16],
                                         float c, float s) {
    // gate [[c, -i*s], [-i*s, c]]; elementwise over the packed wire-0 pair
#pragma unroll
    for (int m = 0; m < 8; ++m) {
        const int lo = m & ((1 << BIT) - 1);
        const int hi = (m >> BIT) << (BIT + 1);
        const int i0 = hi | lo;
        const int i1 = i0 | (1 << BIT);
        const f2 ar = R[i0], ai = I[i0];
        const f2 br = R[i1], bi = I[i1];
        R[i0] = c * ar + s * bi;
        I[i0] = c * ai - s * br;
        R[i1] = c * br + s * ai;
        I[i1] = c * bi - s * ar;
    }
}

// ---- pre-kernel: per (layer L<2, amp m) the packed monomial phase ----
// g[L*16+m] = float4{ Re chi, Re(chi*ephi^cond), Im chi, Im(chi*ephi^cond) }
// chi = product of C-diag factors along the CNOT-walk; cond = final bit3.
__global__ void diag_kernel(const float* __restrict__ thetas,
                            const float* __restrict__ phis,
                            float* __restrict__ g) {
    const int tid = threadIdx.x;
    if (tid >= 32) return;
    const int L = tid >> 4, m = tid & 15;
    float ar[4], ai[4], br[4], bi[4];
#pragma unroll
    for (int k = 0; k < 4; ++k) {
        float sn, cs; sc_half(thetas[4 * L + k], sn, cs);
        ar[k] = sn;  ai[k] = -cs;    // u01 = sin - i cos
        br[k] = -sn; bi[k] = -cs;    // u10 = -sin - i cos
    }
    const int m3 = (m >> 3) & 1, m2 = (m >> 2) & 1, m1 = (m >> 1) & 1, m0 = m & 1;
    float cr = 1.f, ci = 0.f;
#define MULC(xr, xi) { const float nr = cr*(xr) - ci*(xi); \
                       const float ni = cr*(xi) + ci*(xr); cr = nr; ci = ni; }
    // G1: ctrl bit3, tgt bit2 (bits are pre-gate values along the walk)
    if (m3)            { if (m2) MULC(ar[0], ai[0]) else MULC(br[0], bi[0]) }
    const int t2 = m2 ^ m3;
    // G2: ctrl bit2', tgt bit1
    if (t2)            { if (m1) MULC(ar[1], ai[1]) else MULC(br[1], bi[1]) }
    const int t1 = m1 ^ t2;
    // G3: ctrl bit1', tgt bit0
    if (t1)            { if (m0) MULC(ar[2], ai[2]) else MULC(br[2], bi[2]) }
    const int t0 = m0 ^ t1;
    // G4: ctrl bit0', tgt bit3
    if (t0)            { if (m3) MULC(ar[3], ai[3]) else MULC(br[3], bi[3]) }
#undef MULC
    const int cond = m3 ^ t0;            // final bit3 = m0^m1^m2
    float sp_, cp_; sc_full(phis[L], sp_, cp_);
    float cyr = cr, cyi = ci;
    if (cond) { cyr = cr * cp_ - ci * sp_; cyi = cr * sp_ + ci * cp_; }
    float4 o; o.x = cr; o.y = cyr; o.z = ci; o.w = cyi;
    reinterpret_cast<float4*>(g)[L * 16 + m] = o;
}

__global__ __launch_bounds__(256)
void qsim_kernel(const float* __restrict__ x,
                 const float* __restrict__ g,
                 const float* __restrict__ phis,
                 float* __restrict__ out, int P) {
    const int p = blockIdx.x * blockDim.x + threadIdx.x;
    if (p >= P) return;

    const int b   = p >> 14;
    const int rem = p & 16383;
    const int i   = rem >> 7;
    const int j   = rem & 127;

    const float2* __restrict__ x2 = (const float2*)x;
    const long rowbase = (long)b * 768 + 2 * i;   // + c*256 + dy

    // ---- channel 0 loads ----
    float2 v0 = x2[(rowbase + 0) * 128 + j];
    float2 v1 = x2[(rowbase + 1) * 128 + j];

    // ---- fold H(wire0) + layer-0 RX into 16-amp product state ----
    // amp(m) = m(bcde) * (-i)^popcount(bcde); both packed halves identical.
    // (global 1/sqrt2 dropped; cancels the final factor-2 in <Z0>.)
    f2 R[16], I[16];
    {
        float s1, c1, s2, c2, s3, c3, s4, c4;
        sc_half(v0.x, s1, c1);
        sc_half(v0.y, s2, c2);
        sc_half(v1.x, s3, c3);
        sc_half(v1.y, s4, c4);
        const float pA[4] = {c1 * c2, c1 * s2, s1 * c2, s1 * s2}; // bits 3,2
        const float pB[4] = {c3 * c4, c3 * s4, s3 * c4, s3 * s4}; // bits 1,0
#pragma unroll
        for (int m = 0; m < 16; ++m) {
            const float v = pA[m >> 2] * pB[m & 3];
            const int pc = __builtin_popcount((unsigned)m) & 3;
            const float rr = (pc == 0) ? v : ((pc == 2) ? -v : 0.f);
            const float ii = (pc == 1) ? -v : ((pc == 3) ? v : 0.f);
            R[m] = (f2){rr, rr};
            I[m] = (f2){ii, ii};
        }
    }

    // issue channel-1 loads early (consumed in layer-1 RX)
    v0 = x2[(rowbase + 256) * 128 + j];
    v1 = x2[(rowbase + 257) * 128 + j];

    const float4* __restrict__ g4 = (const float4*)g;

    // ---- layer 0 CU block + CPhase(phi0): one monomial (perm + packed diag) ----
    f2 Ra[16], Ia[16];
#pragma unroll
    for (int m = 0; m < 16; ++m) {
        const float4 t = g4[m];
        const f2 gr = {t.x, t.y}, gi = {t.z, t.w};
        const f2 r = R[m], ii = I[m];
        Ra[PI_(m)] = gr * r  - gi * ii;
        Ia[PI_(m)] = gr * ii + gi * r;
    }

    // ---- layer 1 RX ----
    {
        float sn, cs;
        sc_half(v0.x, sn, cs); apply_rx<3>(Ra, Ia, cs, sn);
        sc_half(v0.y, sn, cs); apply_rx<2>(Ra, Ia, cs, sn);
        sc_half(v1.x, sn, cs); apply_rx<1>(Ra, Ia, cs, sn);
        sc_half(v1.y, sn, cs); apply_rx<0>(Ra, Ia, cs, sn);
    }
    // issue channel-2 loads early (consumed in layer-2 RX)
    v0 = x2[(rowbase + 512) * 128 + j];
    v1 = x2[(rowbase + 513) * 128 + j];

    // ---- layer 1 CU block + CPhase(phi1): monomial ----
    f2 Rb[16], Ib[16];
#pragma unroll
    for (int m = 0; m < 16; ++m) {
        const float4 t = g4[16 + m];
        const f2 gr = {t.x, t.y}, gi = {t.z, t.w};
        const f2 r = Ra[m], ii = Ia[m];
        Rb[PI_(m)] = gr * r  - gi * ii;
        Ib[PI_(m)] = gr * ii + gi * r;
    }

    // ---- layer 2 RX ----
    {
        float sn, cs;
        sc_half(v0.x, sn, cs); apply_rx<3>(Rb, Ib, cs, sn);
        sc_half(v0.y, sn, cs); apply_rx<2>(Rb, Ib, cs, sn);
        sc_half(v1.x, sn, cs); apply_rx<1>(Rb, Ib, cs, sn);
        sc_half(v1.y, sn, cs); apply_rx<0>(Rb, Ib, cs, sn);
    }

    // ---- layer 2 CU block is a monomial -> invisible to <Z0>; only the
    // CPhase(phi2) survives, folded into the reduce on amps with final
    // bit3 = m0^m1^m2 = 1 (r1-validated formula). ----
    float ev = 0.f, zr = 0.f, zi = 0.f;
#pragma unroll
    for (int m = 0; m < 16; ++m) {
        const int cond = ((m >> 2) ^ (m >> 1) ^ m) & 1;
        const f2 r = Rb[m], ii = Ib[m];
        const float prr = r.x * r.y + ii.x * ii.y;     // Re(v conj w)
        if (cond) {
            zr += prr;
            zi += ii.x * r.y - r.x * ii.y;             // Im(v conj w)
        } else {
            ev += prr;
        }
    }
    {
        float sn, cs; sc_full(phis[2], sn, cs);
        ev += cs * zr + sn * zi;                        // Re(e^{-i phi2} z)
    }
    out[p] = ev;
}

extern "C" void kernel_launch(void* const* d_in, const int* in_sizes, int n_in,
                              void* d_out, int out_size, void* d_ws, size_t ws_size,
                              hipStream_t stream) {
    const float* x      = (const float*)d_in[0];
    const float* thetas = (const float*)d_in[1];
    const float* phis   = (const float*)d_in[2];
    float* out = (float*)d_out;
    float* g   = (float*)d_ws;            // 128 floats: 2 layers x 16 x float4
    const int P = out_size;               // 16 * 128 * 128 = 262144
    const int threads = 256;
    const int blocks = (P + threads - 1) / threads;
    diag_kernel<<<1, 64, 0, stream>>>(thetas, phis, g);
    qsim_kernel<<<blocks, threads, 0, stream>>>(x, g, phis, out, P);
}